// Round 3
// baseline (1363.513 us; speedup 1.0000x reference)
//
#include <hip/hip_runtime.h>

// Round 9: XCD-local persistent GRU (round-8 base) + two critical-path cuts:
//  (a) decoder FC restructured to full-K per-wave (wave w<4 owns col-tile
//      jf=w, 32 iters, 4-way acc split, NO cross-wave reduce/syncthreads).
//      Waves 4-7 start hpart immediately -> fcdo hides under hpart; inn
//      published by per-wave release atomics (count to 32) ~2us earlier.
//  (b) n-gate weights jf=0 half register-resident (NGr[16], 64 VGPR, loaded
//      once: step-invariant; occupancy is LDS-capped so VGPR<=256 is free).
//      jf=1 half streamed depth-4 (32KB now fits vL1 since A-stream is sc0).

typedef unsigned short ushort_t;
typedef __bf16 bf16x8 __attribute__((ext_vector_type(8)));
typedef float f32x4 __attribute__((ext_vector_type(4)));
typedef unsigned int u32x4 __attribute__((ext_vector_type(4)));

#define MFMA(a, b, c) __builtin_amdgcn_mfma_f32_16x16x32_bf16(a, b, c, 0, 0, 0)

static __device__ __forceinline__ ushort_t f2bf(float f) {
  union { float f; unsigned u; } x; x.f = f;
  unsigned r = x.u + 0x7fffu + ((x.u >> 16) & 1u);
  return (ushort_t)(r >> 16);
}
static __device__ __forceinline__ float sigmf(float x) { return 1.f / (1.f + __expf(-x)); }
static __device__ __forceinline__ float tanhf_(float x) { return 1.f - 2.f / (__expf(2.f * x) + 1.f); }

static __device__ __forceinline__ __amdgpu_buffer_rsrc_t mkrsrc(const void* p) {
  return __builtin_amdgcn_make_buffer_rsrc(const_cast<void*>(p), (short)0, -1, 0x00020000);
}
#if __has_builtin(__builtin_amdgcn_raw_buffer_load_b128)
// aux=1 -> sc0: bypass vL1 (h/inn: written by other CUs each step).
static __device__ __forceinline__ bf16x8 ldb(__amdgpu_buffer_rsrc_t r, int voff) {
  u32x4 v = __builtin_amdgcn_raw_buffer_load_b128(r, voff, 0, 1);
  union { u32x4 u; bf16x8 b; } x; x.u = v; return x.b;
}
// aux=0: vL1-cached (weights: immutable, block/group-private).
static __device__ __forceinline__ bf16x8 ldbc(__amdgpu_buffer_rsrc_t r, int voff) {
  u32x4 v = __builtin_amdgcn_raw_buffer_load_b128(r, voff, 0, 0);
  union { u32x4 u; bf16x8 b; } x; x.u = v; return x.b;
}
#else
static __device__ __forceinline__ bf16x8 ldb(__amdgpu_buffer_rsrc_t r, int voff) {
  union { unsigned u[4]; bf16x8 b; } x;
  x.u[0] = __builtin_amdgcn_raw_buffer_load_b32(r, voff, 0, 1);
  x.u[1] = __builtin_amdgcn_raw_buffer_load_b32(r, voff + 4, 0, 1);
  x.u[2] = __builtin_amdgcn_raw_buffer_load_b32(r, voff + 8, 0, 1);
  x.u[3] = __builtin_amdgcn_raw_buffer_load_b32(r, voff + 12, 0, 1);
  return x.b;
}
static __device__ __forceinline__ bf16x8 ldbc(__amdgpu_buffer_rsrc_t r, int voff) {
  union { unsigned u[4]; bf16x8 b; } x;
  x.u[0] = __builtin_amdgcn_raw_buffer_load_b32(r, voff, 0, 0);
  x.u[1] = __builtin_amdgcn_raw_buffer_load_b32(r, voff + 4, 0, 0);
  x.u[2] = __builtin_amdgcn_raw_buffer_load_b32(r, voff + 8, 0, 0);
  x.u[3] = __builtin_amdgcn_raw_buffer_load_b32(r, voff + 12, 0, 0);
  return x.b;
}
#endif

__global__ __launch_bounds__(512, 2)
void seq2seq_xcd(const float* __restrict__ enc, const float* __restrict__ dec,
                 const float* __restrict__ Wih, const float* __restrict__ Whh,
                 const float* __restrict__ b_ih, const float* __restrict__ b_hh,
                 const float* __restrict__ fcw, const float* __restrict__ fcb,
                 float* __restrict__ outp,
                 ushort_t* __restrict__ xg, ushort_t* __restrict__ hA,
                 ushort_t* __restrict__ innA, ushort_t* __restrict__ nG,
                 ushort_t* __restrict__ fcG, unsigned* cnt) {
  __shared__ ushort_t WrzL[65536];  // [kt32][gate2][jf2][512]  128 KB
  __shared__ ushort_t WiL[6144];    // [kt2][gate3][jf2][512]    12 KB
  __shared__ float scratchF[4096];  // 4 planes x 256 slots x f32x4 (conflict-free) 16 KB
  __shared__ unsigned sgs;

  const int tid = threadIdx.x;
  const int w = tid >> 6, l = tid & 63;
  const int fr = l & 15, fq4 = l >> 4;

  // ---- claim XCD-local slot ----
  if (tid == 0) {
    unsigned x;
    asm volatile("s_getreg_b32 %0, hwreg(HW_REG_XCC_ID, 0, 8)" : "=s"(x));
    x &= 7u;
    unsigned s = atomicAdd(&cnt[x * 64], 1u);
    sgs = (x << 8) | s;
  }
  __syncthreads();
  const int g = sgs >> 8, slot = sgs & 255;
  const bool isFC = (slot >= 24);

  unsigned* arrp = cnt + (8 + g) * 64;
  auto fcpp = [&](int td) { return cnt + (48 + g * 25 + td) * 64; };

  ushort_t* hbase = hA + (size_t)g * 262144;
  auto hb = [&](int i) { return hbase + (size_t)i * 131072; };
  ushort_t* xgg = xg + (size_t)g * 49 * 8192;
  auto inng = [&](int i) { return innA + (size_t)(g * 2 + i) * 8192; };
  ushort_t* nGp = nG + (size_t)(g * 32 + slot) * 32768;
  ushort_t* fcGg = fcG + (size_t)g * 65536;

  // ---- init conversions (all group-local) ----
  for (int i = tid; i < 65536; i += 512) {  // WrzL
    int j = i & 7, ln = (i >> 3) & 63, jf = (i >> 9) & 1, gt = (i >> 10) & 1, kt = i >> 11;
    int col = gt * 1024 + slot * 32 + jf * 16 + (ln & 15);
    int k = kt * 32 + (ln >> 4) * 8 + j;
    WrzL[i] = f2bf(Whh[(size_t)col * 1024 + k]);
  }
  for (int i = tid; i < 6144; i += 512) {  // WiL (r,z,n)
    int j = i & 7, ln = (i >> 3) & 63, jf = (i >> 9) & 1, rem = i >> 10;
    int gt = rem % 3, kt = rem / 3;
    int col = gt * 1024 + slot * 32 + jf * 16 + (ln & 15);
    int k = kt * 32 + (ln >> 4) * 8 + j;
    WiL[i] = (k < 55) ? f2bf(Wih[(size_t)col * 55 + k]) : (ushort_t)0;
  }
  for (int i = tid; i < 32768; i += 512) {  // nG (block-private)
    int j = i & 7, ln = (i >> 3) & 63, jf = (i >> 9) & 1, kt = i >> 10;
    int col = 2048 + slot * 32 + jf * 16 + (ln & 15);
    int k = kt * 32 + (ln >> 4) * 8 + j;
    nGp[i] = f2bf(Whh[(size_t)col * 1024 + k]);
  }
#pragma unroll
  for (int rep = 0; rep < 2; ++rep) {  // xg: t = slot, slot+32
    int t = slot + rep * 32;
    if (t < 49) {
      ushort_t* xp = xgg + (size_t)t * 8192;
      for (int i = tid; i < 8192; i += 512) {
        int sub = i & 7, row = (i >> 3) & 127, kc = i >> 10;
        int c = kc * 8 + sub;
        xp[i] = (c < 55) ? f2bf(enc[((size_t)(g * 128 + row) * 50 + t) * 55 + c]) : (ushort_t)0;
      }
    }
  }
  if (slot < 4) {  // inn(0) = dec[:,0,:]
    ushort_t* ip = inng(0);
    for (int i = slot * 2048 + tid; i < (slot + 1) * 2048; i += 512) {
      int sub = i & 7, row = (i >> 3) & 127, kc = i >> 10;
      int c = kc * 8 + sub;
      ip[i] = (c < 55) ? f2bf(dec[(size_t)(g * 128 + row) * 1375 + c]) : (ushort_t)0;
    }
  }
  if (isFC) {  // fcG: group-shared, slot s converts kt 4(s-24)..+3
    for (int i = (slot - 24) * 8192 + tid; i < (slot - 23) * 8192; i += 512) {
      int j = i & 7, ln = (i >> 3) & 63, jf = (i >> 9) & 3, kt = i >> 11;
      int c = jf * 16 + (ln & 15);
      int k = kt * 32 + (ln >> 4) * 8 + j;
      fcGg[i] = (c < 55) ? f2bf(fcw[(size_t)c * 1024 + k]) : (ushort_t)0;
    }
  }

  // ---- per-thread constants ----
  float brz[2], bzz[2], bin[2], bhn[2];
#pragma unroll
  for (int jf = 0; jf < 2; ++jf) {
    int col = slot * 32 + jf * 16 + fr;
    brz[jf] = b_ih[col] + b_hh[col];
    bzz[jf] = b_ih[1024 + col] + b_hh[1024 + col];
    bin[jf] = b_ih[2048 + col];
    bhn[jf] = b_hh[2048 + col];
  }
  const int Rfc = (slot - 24) * 16;      // FC block rows (if isFC)
  const int jfF = w & 3;
  const int colF = jfF * 16 + fr;
  float fcbF = 0.f, inp[4] = {0.f, 0.f, 0.f, 0.f};
  if (isFC && w < 4) {
    fcbF = (colF < 55) ? fcb[colF] : 0.f;
#pragma unroll
    for (int v = 0; v < 4; ++v)
      inp[v] = (colF < 55) ? dec[(size_t)(g * 128 + Rfc + fq4 * 4 + v) * 1375 + colF] : 0.f;
  }
  f32x4 hreg[4];  // waves 0-3: [mi*2+jf]
#pragma unroll
  for (int i = 0; i < 4; ++i) hreg[i] = (f32x4){0.f, 0.f, 0.f, 0.f};

  // ---- flat group barrier (group = one XCD; no cache maintenance) ----
  auto arrive = [&](unsigned k) {
    (void)k;
    __syncthreads();  // drains vmcnt: all stores complete at (shared) L2
    if (tid == 0) atomicAdd(arrp, 1u);
  };
  auto wait_rel = [&](unsigned k) {
    __syncthreads();
    if (tid == 0) {
      while (__hip_atomic_load(arrp, __ATOMIC_RELAXED, __HIP_MEMORY_SCOPE_AGENT) < 32u * k)
        __builtin_amdgcn_s_sleep(1);
    }
    __syncthreads();
  };
  auto fc_wait = [&](int td) {  // 8 FC blocks x 4 waves = 32 wave-arrivals
    __syncthreads();
    if (tid == 0) {
      while (__hip_atomic_load(fcpp(td), __ATOMIC_RELAXED, __HIP_MEMORY_SCOPE_AGENT) < 32u)
        __builtin_amdgcn_s_sleep(1);
    }
    __syncthreads();
  };

  // ---- accumulators: r/z/nH K-split in av[12]; nX on waves 0-3 ----
  f32x4 av[12], nx[4];
  bf16x8 NGr[16];  // resident n-gate weights, jf=0 half (step-invariant)

  auto xpart = [&](const ushort_t* xp) {  // waves 0-3 only; full K=64
    __amdgpu_buffer_rsrc_t rx = mkrsrc(xp);
    const int R = w * 32;
#pragma unroll
    for (int kt = 0; kt < 2; ++kt) {
      bf16x8 a0 = ldb(rx, ((kt * 4 + fq4) * 128 + R + fr) * 16);
      bf16x8 a1 = ldb(rx, ((kt * 4 + fq4) * 128 + R + 16 + fr) * 16);
      const ushort_t* bl = WiL + kt * 3072 + l * 8;
#pragma unroll
      for (int jf = 0; jf < 2; ++jf) {
        bf16x8 br = *(const bf16x8*)(bl + jf * 512);
        bf16x8 bz = *(const bf16x8*)(bl + 1024 + jf * 512);
        bf16x8 bn = *(const bf16x8*)(bl + 2048 + jf * 512);
        av[jf] = MFMA(a0, br, av[jf]);
        av[2 + jf] = MFMA(a1, br, av[2 + jf]);
        av[4 + jf] = MFMA(a0, bz, av[4 + jf]);
        av[6 + jf] = MFMA(a1, bz, av[6 + jf]);
        nx[jf] = MFMA(a0, bn, nx[jf]);
        nx[2 + jf] = MFMA(a1, bn, nx[2 + jf]);
      }
    }
  };

  auto hpart = [&](const ushort_t* hbp) {  // all waves; K-split halves
    __amdgpu_buffer_rsrc_t r = mkrsrc(hbp);
    __amdgpu_buffer_rsrc_t rn = mkrsrc(nGp);
    const int kh = w >> 2, R = (w & 3) * 32;
    bf16x8 A0[4], A1[4];   // h fragments: depth-4 prefetch (sc0, L2)
    bf16x8 N1[4];          // n-gate jf=1 stream: depth-4 prefetch (vL1)
#pragma unroll
    for (int i = 0; i < 4; ++i) {
      int kt = kh * 16 + i;
      A0[i] = ldb(r, ((kt * 4 + fq4) * 128 + R + fr) * 16);
      A1[i] = ldb(r, ((kt * 4 + fq4) * 128 + R + 16 + fr) * 16);
      N1[i] = ldbc(rn, kt * 2048 + 1024 + l * 16);
    }
#pragma unroll
    for (int i = 0; i < 16; ++i) {
      int kt = kh * 16 + i;
      bf16x8 a0 = A0[i & 3], a1 = A1[i & 3];
      bf16x8 n0 = NGr[i], n1 = N1[i & 3];
      if (i < 12) {
        int kp = kt + 4;
        A0[i & 3] = ldb(r, ((kp * 4 + fq4) * 128 + R + fr) * 16);
        A1[i & 3] = ldb(r, ((kp * 4 + fq4) * 128 + R + 16 + fr) * 16);
        N1[i & 3] = ldbc(rn, kp * 2048 + 1024 + l * 16);
      }
      const ushort_t* bl = WrzL + kt * 2048 + l * 8;
#pragma unroll
      for (int jf = 0; jf < 2; ++jf) {
        bf16x8 br = *(const bf16x8*)(bl + jf * 512);
        bf16x8 bz = *(const bf16x8*)(bl + 1024 + jf * 512);
        bf16x8 bn = (jf == 0) ? n0 : n1;
        av[jf] = MFMA(a0, br, av[jf]);
        av[2 + jf] = MFMA(a1, br, av[2 + jf]);
        av[4 + jf] = MFMA(a0, bz, av[4 + jf]);
        av[6 + jf] = MFMA(a1, bz, av[6 + jf]);
        av[8 + jf] = MFMA(a0, bn, av[8 + jf]);
        av[10 + jf] = MFMA(a1, bn, av[10 + jf]);
      }
    }
  };

  // waves 4-7 partials -> waves 0-3. Plane layout: scratchF[r*1024 + slot*4],
  // slot = wave4*64 + lane -> 16B/lane contiguous per wave => conflict-free.
  auto kreduce = [&]() {
#pragma unroll
    for (int rd = 0; rd < 3; ++rd) {
      if (w >= 4) {
        float* sp = scratchF + ((w - 4) * 64 + l) * 4;
#pragma unroll
        for (int r = 0; r < 4; ++r)
          *(f32x4*)(sp + r * 1024) = av[rd * 4 + r];
      }
      __syncthreads();
      if (w < 4) {
        const float* sp = scratchF + (w * 64 + l) * 4;
#pragma unroll
        for (int r = 0; r < 4; ++r)
          av[rd * 4 + r] += *(const f32x4*)(sp + r * 1024);
      }
      __syncthreads();
    }
  };

  // FC: full-K per-wave (waves 0-3 only; wave w owns col-tile jf=w).
  // No scratch, no syncthreads -> runs concurrently with waves 4-7's hpart.
  auto fcdo_w = [&](const ushort_t* hbp, int td, bool wr, ushort_t* innW) {
    __amdgpu_buffer_rsrc_t r = mkrsrc(hbp);
    __amdgpu_buffer_rsrc_t rf = mkrsrc(fcGg);
    f32x4 fa4[4];
#pragma unroll
    for (int i = 0; i < 4; ++i) fa4[i] = (f32x4){0.f, 0.f, 0.f, 0.f};
    bf16x8 Af[4], Bf[4];
#pragma unroll
    for (int i = 0; i < 4; ++i) {
      Af[i] = ldb(r, ((i * 4 + fq4) * 128 + Rfc + fr) * 16);
      Bf[i] = ldbc(rf, (i * 4 + jfF) * 1024 + l * 16);
    }
#pragma unroll
    for (int i = 0; i < 32; ++i) {
      bf16x8 a = Af[i & 3], bb = Bf[i & 3];
      if (i < 28) {
        Af[i & 3] = ldb(r, (((i + 4) * 4 + fq4) * 128 + Rfc + fr) * 16);
        Bf[i & 3] = ldbc(rf, ((i + 4) * 4 + jfF) * 1024 + l * 16);
      }
      fa4[i & 3] = MFMA(a, bb, fa4[i & 3]);
    }
    f32x4 fa = (fa4[0] + fa4[1]) + (fa4[2] + fa4[3]);
    const int kq = colF >> 3, sub = colF & 7;
#pragma unroll
    for (int v = 0; v < 4; ++v) {
      int row = Rfc + fq4 * 4 + v;
      float o = fa[v] + inp[v] + fcbF;
      inp[v] = o;
      if (wr) innW[(kq * 128 + row) * 8 + sub] = f2bf(o);
      if (colF < 55) outp[(size_t)(g * 128 + row) * 1375 + td * 55 + colF] = o;
    }
  };

  arrive(1);
  wait_rel(1);

  {  // resident n-gate jf=0 weights (after own-block staging is drained)
    __amdgpu_buffer_rsrc_t rn = mkrsrc(nGp);
    const int kh = w >> 2;
#pragma unroll
    for (int i = 0; i < 16; ++i)
      NGr[i] = ldbc(rn, (kh * 16 + i) * 2048 + l * 16);
  }

  for (int t = 0; t < 74; ++t) {
#pragma unroll
    for (int i = 0; i < 12; ++i) av[i] = (f32x4){0.f, 0.f, 0.f, 0.f};
#pragma unroll
    for (int i = 0; i < 4; ++i) nx[i] = (f32x4){0.f, 0.f, 0.f, 0.f};

    if (t <= 49) {
      if (w < 4) xpart(t <= 48 ? xgg + (size_t)t * 8192 : inng(0));
    }
    if (t > 0) wait_rel(t + 1);
    if (t >= 50 && isFC && w < 4) {
      fcdo_w(hb(t & 1), t - 50, true, inng((t - 49) & 1));
      if (l == 0)
        __hip_atomic_fetch_add(fcpp(t - 50), 1u, __ATOMIC_RELEASE, __HIP_MEMORY_SCOPE_AGENT);
    }
    if (t > 0) hpart(hb(t & 1));
    if (t >= 50) {
      fc_wait(t - 50);
      if (w < 4) xpart(inng((t - 49) & 1));
    }
    kreduce();
    if (w < 4) {  // epilogue: gates + fp32 carry + publish bf16 h(t+1)
      ushort_t* hn = hb((t + 1) & 1);
#pragma unroll
      for (int mi = 0; mi < 2; ++mi)
#pragma unroll
        for (int jf = 0; jf < 2; ++jf) {
          f32x4 R_ = av[mi * 2 + jf], Z_ = av[4 + mi * 2 + jf];
          f32x4 NH = av[8 + mi * 2 + jf], NX = nx[mi * 2 + jf];
          const int kq = slot * 4 + jf * 2 + (fr >> 3), sub = fr & 7;
#pragma unroll
          for (int v = 0; v < 4; ++v) {
            float rr = sigmf(R_[v] + brz[jf]);
            float zz = sigmf(Z_[v] + bzz[jf]);
            float nn = tanhf_(NX[v] + bin[jf] + rr * (NH[v] + bhn[jf]));
            float h = (1.f - zz) * nn + zz * hreg[mi * 2 + jf][v];
            hreg[mi * 2 + jf][v] = h;
            int row = w * 32 + mi * 16 + fq4 * 4 + v;
            hn[(kq * 128 + row) * 8 + sub] = f2bf(h);
          }
        }
    }
    arrive(t + 2);
  }

  if (isFC) {
    wait_rel(75);
    if (w < 4) fcdo_w(hb(0), 24, false, (ushort_t*)0);
  }
}

extern "C" void kernel_launch(void* const* d_in, const int* in_sizes, int n_in,
                              void* d_out, int out_size, void* d_ws, size_t ws_size,
                              hipStream_t stream) {
  const float* enc  = (const float*)d_in[0];
  const float* dec  = (const float*)d_in[1];
  const float* Wih  = (const float*)d_in[2];
  const float* Whh  = (const float*)d_in[3];
  const float* b_ih = (const float*)d_in[4];
  const float* b_hh = (const float*)d_in[5];
  const float* fcw  = (const float*)d_in[6];
  const float* fcb  = (const float*)d_in[7];
  float* out = (float*)d_out;

  char* ws = (char*)d_ws;
  unsigned* cnt  = (unsigned*)ws; ws += 65536;
  ushort_t* xg   = (ushort_t*)ws; ws += (size_t)8 * 49 * 8192 * 2;   // 6.42 MB
  ushort_t* hA   = (ushort_t*)ws; ws += (size_t)8 * 2 * 131072 * 2;  // 4 MB
  ushort_t* innA = (ushort_t*)ws; ws += (size_t)8 * 2 * 8192 * 2;    // 256 KB
  ushort_t* nG   = (ushort_t*)ws; ws += (size_t)8 * 32 * 32768 * 2;  // 16 MB
  ushort_t* fcG  = (ushort_t*)ws; ws += (size_t)8 * 65536 * 2;       // 1 MB

  (void)hipMemsetAsync(cnt, 0, 65536, stream);
  seq2seq_xcd<<<256, 512, 0, stream>>>(
      enc, dec, Wih, Whh, b_ih, b_hh, fcw, fcb, out,
      xg, hA, innA, nG, fcG, cnt);
}

// Round 4
// 1135.013 us; speedup vs baseline: 1.2013x; 1.2013x over previous
//
#include <hip/hip_runtime.h>

// Round 10: R8 base (945us) + targeted fixes after R9 post-mortem:
//  - NGr register-residency REVERTED (compiler spilled it to scratch: VGPR
//    stayed 128, FETCH/WRITE grew, all steps slowed). n-gate jf0/jf1 both
//    streamed depth-4 from L2/vL1 as in R8.
//  - fcdo kept per-wave full-K (waves 4-7 enter hpart immediately), but inn
//    release = explicit s_waitcnt vmcnt(0) + RELAXED atomic (no agent-RELEASE
//    cache maintenance; same-XCD consumers read via sc0 -> L2 visibility ok).
//  - wait_rel/fc_wait: per-wave polling (no block syncthreads on acquire
//    side; arrive keeps syncthreads to drain h stores). -4 syncs/step.

typedef unsigned short ushort_t;
typedef __bf16 bf16x8 __attribute__((ext_vector_type(8)));
typedef float f32x4 __attribute__((ext_vector_type(4)));
typedef unsigned int u32x4 __attribute__((ext_vector_type(4)));

#define MFMA(a, b, c) __builtin_amdgcn_mfma_f32_16x16x32_bf16(a, b, c, 0, 0, 0)

static __device__ __forceinline__ ushort_t f2bf(float f) {
  union { float f; unsigned u; } x; x.f = f;
  unsigned r = x.u + 0x7fffu + ((x.u >> 16) & 1u);
  return (ushort_t)(r >> 16);
}
static __device__ __forceinline__ float sigmf(float x) { return 1.f / (1.f + __expf(-x)); }
static __device__ __forceinline__ float tanhf_(float x) { return 1.f - 2.f / (__expf(2.f * x) + 1.f); }

static __device__ __forceinline__ __amdgpu_buffer_rsrc_t mkrsrc(const void* p) {
  return __builtin_amdgcn_make_buffer_rsrc(const_cast<void*>(p), (short)0, -1, 0x00020000);
}
#if __has_builtin(__builtin_amdgcn_raw_buffer_load_b128)
// aux=1 -> sc0: bypass vL1 (h/inn: written by other CUs each step).
static __device__ __forceinline__ bf16x8 ldb(__amdgpu_buffer_rsrc_t r, int voff) {
  u32x4 v = __builtin_amdgcn_raw_buffer_load_b128(r, voff, 0, 1);
  union { u32x4 u; bf16x8 b; } x; x.u = v; return x.b;
}
// aux=0: vL1-cached (weights: immutable, block/group-private).
static __device__ __forceinline__ bf16x8 ldbc(__amdgpu_buffer_rsrc_t r, int voff) {
  u32x4 v = __builtin_amdgcn_raw_buffer_load_b128(r, voff, 0, 0);
  union { u32x4 u; bf16x8 b; } x; x.u = v; return x.b;
}
#else
static __device__ __forceinline__ bf16x8 ldb(__amdgpu_buffer_rsrc_t r, int voff) {
  union { unsigned u[4]; bf16x8 b; } x;
  x.u[0] = __builtin_amdgcn_raw_buffer_load_b32(r, voff, 0, 1);
  x.u[1] = __builtin_amdgcn_raw_buffer_load_b32(r, voff + 4, 0, 1);
  x.u[2] = __builtin_amdgcn_raw_buffer_load_b32(r, voff + 8, 0, 1);
  x.u[3] = __builtin_amdgcn_raw_buffer_load_b32(r, voff + 12, 0, 1);
  return x.b;
}
static __device__ __forceinline__ bf16x8 ldbc(__amdgpu_buffer_rsrc_t r, int voff) {
  union { unsigned u[4]; bf16x8 b; } x;
  x.u[0] = __builtin_amdgcn_raw_buffer_load_b32(r, voff, 0, 0);
  x.u[1] = __builtin_amdgcn_raw_buffer_load_b32(r, voff + 4, 0, 0);
  x.u[2] = __builtin_amdgcn_raw_buffer_load_b32(r, voff + 8, 0, 0);
  x.u[3] = __builtin_amdgcn_raw_buffer_load_b32(r, voff + 12, 0, 0);
  return x.b;
}
#endif

__global__ __launch_bounds__(512, 2)
void seq2seq_xcd(const float* __restrict__ enc, const float* __restrict__ dec,
                 const float* __restrict__ Wih, const float* __restrict__ Whh,
                 const float* __restrict__ b_ih, const float* __restrict__ b_hh,
                 const float* __restrict__ fcw, const float* __restrict__ fcb,
                 float* __restrict__ outp,
                 ushort_t* __restrict__ xg, ushort_t* __restrict__ hA,
                 ushort_t* __restrict__ innA, ushort_t* __restrict__ nG,
                 ushort_t* __restrict__ fcG, unsigned* cnt) {
  __shared__ ushort_t WrzL[65536];  // [kt32][gate2][jf2][512]  128 KB
  __shared__ ushort_t WiL[6144];    // [kt2][gate3][jf2][512]    12 KB
  __shared__ float scratchF[4096];  // 4 planes x 256 slots x f32x4 (conflict-free) 16 KB
  __shared__ unsigned sgs;

  const int tid = threadIdx.x;
  const int w = tid >> 6, l = tid & 63;
  const int fr = l & 15, fq4 = l >> 4;

  // ---- claim XCD-local slot ----
  if (tid == 0) {
    unsigned x;
    asm volatile("s_getreg_b32 %0, hwreg(HW_REG_XCC_ID, 0, 8)" : "=s"(x));
    x &= 7u;
    unsigned s = atomicAdd(&cnt[x * 64], 1u);
    sgs = (x << 8) | s;
  }
  __syncthreads();
  const int g = sgs >> 8, slot = sgs & 255;
  const bool isFC = (slot >= 24);

  unsigned* arrp = cnt + (8 + g) * 64;
  auto fcpp = [&](int td) { return cnt + (48 + g * 25 + td) * 64; };

  ushort_t* hbase = hA + (size_t)g * 262144;
  auto hb = [&](int i) { return hbase + (size_t)i * 131072; };
  ushort_t* xgg = xg + (size_t)g * 49 * 8192;
  auto inng = [&](int i) { return innA + (size_t)(g * 2 + i) * 8192; };
  ushort_t* nGp = nG + (size_t)(g * 32 + slot) * 32768;
  ushort_t* fcGg = fcG + (size_t)g * 65536;

  // ---- init conversions (all group-local) ----
  for (int i = tid; i < 65536; i += 512) {  // WrzL
    int j = i & 7, ln = (i >> 3) & 63, jf = (i >> 9) & 1, gt = (i >> 10) & 1, kt = i >> 11;
    int col = gt * 1024 + slot * 32 + jf * 16 + (ln & 15);
    int k = kt * 32 + (ln >> 4) * 8 + j;
    WrzL[i] = f2bf(Whh[(size_t)col * 1024 + k]);
  }
  for (int i = tid; i < 6144; i += 512) {  // WiL (r,z,n)
    int j = i & 7, ln = (i >> 3) & 63, jf = (i >> 9) & 1, rem = i >> 10;
    int gt = rem % 3, kt = rem / 3;
    int col = gt * 1024 + slot * 32 + jf * 16 + (ln & 15);
    int k = kt * 32 + (ln >> 4) * 8 + j;
    WiL[i] = (k < 55) ? f2bf(Wih[(size_t)col * 55 + k]) : (ushort_t)0;
  }
  for (int i = tid; i < 32768; i += 512) {  // nG (block-private)
    int j = i & 7, ln = (i >> 3) & 63, jf = (i >> 9) & 1, kt = i >> 10;
    int col = 2048 + slot * 32 + jf * 16 + (ln & 15);
    int k = kt * 32 + (ln >> 4) * 8 + j;
    nGp[i] = f2bf(Whh[(size_t)col * 1024 + k]);
  }
#pragma unroll
  for (int rep = 0; rep < 2; ++rep) {  // xg: t = slot, slot+32
    int t = slot + rep * 32;
    if (t < 49) {
      ushort_t* xp = xgg + (size_t)t * 8192;
      for (int i = tid; i < 8192; i += 512) {
        int sub = i & 7, row = (i >> 3) & 127, kc = i >> 10;
        int c = kc * 8 + sub;
        xp[i] = (c < 55) ? f2bf(enc[((size_t)(g * 128 + row) * 50 + t) * 55 + c]) : (ushort_t)0;
      }
    }
  }
  if (slot < 4) {  // inn(0) = dec[:,0,:]
    ushort_t* ip = inng(0);
    for (int i = slot * 2048 + tid; i < (slot + 1) * 2048; i += 512) {
      int sub = i & 7, row = (i >> 3) & 127, kc = i >> 10;
      int c = kc * 8 + sub;
      ip[i] = (c < 55) ? f2bf(dec[(size_t)(g * 128 + row) * 1375 + c]) : (ushort_t)0;
    }
  }
  if (isFC) {  // fcG: group-shared, slot s converts kt 4(s-24)..+3
    for (int i = (slot - 24) * 8192 + tid; i < (slot - 23) * 8192; i += 512) {
      int j = i & 7, ln = (i >> 3) & 63, jf = (i >> 9) & 3, kt = i >> 11;
      int c = jf * 16 + (ln & 15);
      int k = kt * 32 + (ln >> 4) * 8 + j;
      fcGg[i] = (c < 55) ? f2bf(fcw[(size_t)c * 1024 + k]) : (ushort_t)0;
    }
  }

  // ---- per-thread constants ----
  float brz[2], bzz[2], bin[2], bhn[2];
#pragma unroll
  for (int jf = 0; jf < 2; ++jf) {
    int col = slot * 32 + jf * 16 + fr;
    brz[jf] = b_ih[col] + b_hh[col];
    bzz[jf] = b_ih[1024 + col] + b_hh[1024 + col];
    bin[jf] = b_ih[2048 + col];
    bhn[jf] = b_hh[2048 + col];
  }
  const int Rfc = (slot - 24) * 16;      // FC block rows (if isFC)
  const int jfF = w & 3;
  const int colF = jfF * 16 + fr;
  float fcbF = 0.f, inp[4] = {0.f, 0.f, 0.f, 0.f};
  if (isFC && w < 4) {
    fcbF = (colF < 55) ? fcb[colF] : 0.f;
#pragma unroll
    for (int v = 0; v < 4; ++v)
      inp[v] = (colF < 55) ? dec[(size_t)(g * 128 + Rfc + fq4 * 4 + v) * 1375 + colF] : 0.f;
  }
  f32x4 hreg[4];  // waves 0-3: [mi*2+jf]
#pragma unroll
  for (int i = 0; i < 4; ++i) hreg[i] = (f32x4){0.f, 0.f, 0.f, 0.f};

  // ---- flat group barrier; acquire side is PER-WAVE (no block syncs) ----
  auto arrive = [&](unsigned k) {
    (void)k;
    __syncthreads();  // drains vmcnt: all stores complete at (shared) L2
    if (tid == 0) atomicAdd(arrp, 1u);
  };
  auto wait_rel = [&](unsigned k) {  // each wave polls independently
    while (__hip_atomic_load(arrp, __ATOMIC_RELAXED, __HIP_MEMORY_SCOPE_AGENT) < 32u * k)
      __builtin_amdgcn_s_sleep(1);
  };
  auto fc_wait = [&](int td) {  // 8 FC blocks x 4 waves = 32 wave-arrivals
    while (__hip_atomic_load(fcpp(td), __ATOMIC_RELAXED, __HIP_MEMORY_SCOPE_AGENT) < 32u)
      __builtin_amdgcn_s_sleep(1);
  };

  // ---- accumulators: r/z/nH K-split in av[12]; nX on waves 0-3 ----
  f32x4 av[12], nx[4];

  auto xpart = [&](const ushort_t* xp) {  // waves 0-3 only; full K=64
    __amdgpu_buffer_rsrc_t rx = mkrsrc(xp);
    const int R = w * 32;
#pragma unroll
    for (int kt = 0; kt < 2; ++kt) {
      bf16x8 a0 = ldb(rx, ((kt * 4 + fq4) * 128 + R + fr) * 16);
      bf16x8 a1 = ldb(rx, ((kt * 4 + fq4) * 128 + R + 16 + fr) * 16);
      const ushort_t* bl = WiL + kt * 3072 + l * 8;
#pragma unroll
      for (int jf = 0; jf < 2; ++jf) {
        bf16x8 br = *(const bf16x8*)(bl + jf * 512);
        bf16x8 bz = *(const bf16x8*)(bl + 1024 + jf * 512);
        bf16x8 bn = *(const bf16x8*)(bl + 2048 + jf * 512);
        av[jf] = MFMA(a0, br, av[jf]);
        av[2 + jf] = MFMA(a1, br, av[2 + jf]);
        av[4 + jf] = MFMA(a0, bz, av[4 + jf]);
        av[6 + jf] = MFMA(a1, bz, av[6 + jf]);
        nx[jf] = MFMA(a0, bn, nx[jf]);
        nx[2 + jf] = MFMA(a1, bn, nx[2 + jf]);
      }
    }
  };

  auto hpart = [&](const ushort_t* hbp) {  // all waves; K-split halves
    __amdgpu_buffer_rsrc_t r = mkrsrc(hbp);
    __amdgpu_buffer_rsrc_t rn = mkrsrc(nGp);
    const int kh = w >> 2, R = (w & 3) * 32;
    bf16x8 A0[4], A1[4];   // h fragments: depth-4 prefetch (sc0, L2)
    bf16x8 NG[4][2];       // n-gate weights: depth-4 prefetch (vL1)
#pragma unroll
    for (int i = 0; i < 4; ++i) {
      int kt = kh * 16 + i;
      A0[i] = ldb(r, ((kt * 4 + fq4) * 128 + R + fr) * 16);
      A1[i] = ldb(r, ((kt * 4 + fq4) * 128 + R + 16 + fr) * 16);
      NG[i][0] = ldbc(rn, kt * 2048 + l * 16);
      NG[i][1] = ldbc(rn, kt * 2048 + 1024 + l * 16);
    }
#pragma unroll
    for (int i = 0; i < 16; ++i) {
      int kt = kh * 16 + i;
      bf16x8 a0 = A0[i & 3], a1 = A1[i & 3];
      bf16x8 n0 = NG[i & 3][0], n1 = NG[i & 3][1];
      if (i < 12) {
        int kp = kt + 4;
        A0[i & 3] = ldb(r, ((kp * 4 + fq4) * 128 + R + fr) * 16);
        A1[i & 3] = ldb(r, ((kp * 4 + fq4) * 128 + R + 16 + fr) * 16);
        NG[i & 3][0] = ldbc(rn, kp * 2048 + l * 16);
        NG[i & 3][1] = ldbc(rn, kp * 2048 + 1024 + l * 16);
      }
      const ushort_t* bl = WrzL + kt * 2048 + l * 8;
#pragma unroll
      for (int jf = 0; jf < 2; ++jf) {
        bf16x8 br = *(const bf16x8*)(bl + jf * 512);
        bf16x8 bz = *(const bf16x8*)(bl + 1024 + jf * 512);
        bf16x8 bn = (jf == 0) ? n0 : n1;
        av[jf] = MFMA(a0, br, av[jf]);
        av[2 + jf] = MFMA(a1, br, av[2 + jf]);
        av[4 + jf] = MFMA(a0, bz, av[4 + jf]);
        av[6 + jf] = MFMA(a1, bz, av[6 + jf]);
        av[8 + jf] = MFMA(a0, bn, av[8 + jf]);
        av[10 + jf] = MFMA(a1, bn, av[10 + jf]);
      }
    }
  };

  // waves 4-7 partials -> waves 0-3. Plane layout: scratchF[r*1024 + slot*4],
  // slot = wave4*64 + lane -> 16B/lane contiguous per wave => conflict-free.
  auto kreduce = [&]() {
#pragma unroll
    for (int rd = 0; rd < 3; ++rd) {
      if (w >= 4) {
        float* sp = scratchF + ((w - 4) * 64 + l) * 4;
#pragma unroll
        for (int r = 0; r < 4; ++r)
          *(f32x4*)(sp + r * 1024) = av[rd * 4 + r];
      }
      __syncthreads();
      if (w < 4) {
        const float* sp = scratchF + (w * 64 + l) * 4;
#pragma unroll
        for (int r = 0; r < 4; ++r)
          av[rd * 4 + r] += *(const f32x4*)(sp + r * 1024);
      }
      __syncthreads();
    }
  };

  // FC: full-K per-wave (waves 0-3 only; wave w owns col-tile jf=w).
  // No scratch, no syncthreads -> runs concurrently with waves 4-7's hpart.
  auto fcdo_w = [&](const ushort_t* hbp, int td, bool wr, ushort_t* innW) {
    __amdgpu_buffer_rsrc_t r = mkrsrc(hbp);
    __amdgpu_buffer_rsrc_t rf = mkrsrc(fcGg);
    f32x4 fa4[4];
#pragma unroll
    for (int i = 0; i < 4; ++i) fa4[i] = (f32x4){0.f, 0.f, 0.f, 0.f};
    bf16x8 Af[4], Bf[4];
#pragma unroll
    for (int i = 0; i < 4; ++i) {
      Af[i] = ldb(r, ((i * 4 + fq4) * 128 + Rfc + fr) * 16);
      Bf[i] = ldbc(rf, (i * 4 + jfF) * 1024 + l * 16);
    }
#pragma unroll
    for (int i = 0; i < 32; ++i) {
      bf16x8 a = Af[i & 3], bb = Bf[i & 3];
      if (i < 28) {
        Af[i & 3] = ldb(r, (((i + 4) * 4 + fq4) * 128 + Rfc + fr) * 16);
        Bf[i & 3] = ldbc(rf, ((i + 4) * 4 + jfF) * 1024 + l * 16);
      }
      fa4[i & 3] = MFMA(a, bb, fa4[i & 3]);
    }
    f32x4 fa = (fa4[0] + fa4[1]) + (fa4[2] + fa4[3]);
    const int kq = colF >> 3, sub = colF & 7;
#pragma unroll
    for (int v = 0; v < 4; ++v) {
      int row = Rfc + fq4 * 4 + v;
      float o = fa[v] + inp[v] + fcbF;
      inp[v] = o;
      if (wr) innW[(kq * 128 + row) * 8 + sub] = f2bf(o);
      if (colF < 55) outp[(size_t)(g * 128 + row) * 1375 + td * 55 + colF] = o;
    }
    if (wr) {
      asm volatile("s_waitcnt vmcnt(0)" ::: "memory");  // inn stores at L2
      if (l == 0)
        __hip_atomic_fetch_add(fcpp(td), 1u, __ATOMIC_RELAXED, __HIP_MEMORY_SCOPE_AGENT);
    }
  };

  arrive(1);
  wait_rel(1);

  for (int t = 0; t < 74; ++t) {
#pragma unroll
    for (int i = 0; i < 12; ++i) av[i] = (f32x4){0.f, 0.f, 0.f, 0.f};
#pragma unroll
    for (int i = 0; i < 4; ++i) nx[i] = (f32x4){0.f, 0.f, 0.f, 0.f};

    if (t <= 49) {
      if (w < 4) xpart(t <= 48 ? xgg + (size_t)t * 8192 : inng(0));
    }
    if (t > 0) wait_rel(t + 1);
    if (t >= 50 && isFC && w < 4)
      fcdo_w(hb(t & 1), t - 50, true, inng((t - 49) & 1));
    if (t > 0) hpart(hb(t & 1));
    if (t >= 50) {
      fc_wait(t - 50);
      if (w < 4) xpart(inng((t - 49) & 1));
    }
    kreduce();
    if (w < 4) {  // epilogue: gates + fp32 carry + publish bf16 h(t+1)
      ushort_t* hn = hb((t + 1) & 1);
#pragma unroll
      for (int mi = 0; mi < 2; ++mi)
#pragma unroll
        for (int jf = 0; jf < 2; ++jf) {
          f32x4 R_ = av[mi * 2 + jf], Z_ = av[4 + mi * 2 + jf];
          f32x4 NH = av[8 + mi * 2 + jf], NX = nx[mi * 2 + jf];
          const int kq = slot * 4 + jf * 2 + (fr >> 3), sub = fr & 7;
#pragma unroll
          for (int v = 0; v < 4; ++v) {
            float rr = sigmf(R_[v] + brz[jf]);
            float zz = sigmf(Z_[v] + bzz[jf]);
            float nn = tanhf_(NX[v] + bin[jf] + rr * (NH[v] + bhn[jf]));
            float h = (1.f - zz) * nn + zz * hreg[mi * 2 + jf][v];
            hreg[mi * 2 + jf][v] = h;
            int row = w * 32 + mi * 16 + fq4 * 4 + v;
            hn[(kq * 128 + row) * 8 + sub] = f2bf(h);
          }
        }
    }
    arrive(t + 2);
  }

  if (isFC) {
    wait_rel(75);
    if (w < 4) fcdo_w(hb(0), 24, false, (ushort_t*)0);
  }
}

extern "C" void kernel_launch(void* const* d_in, const int* in_sizes, int n_in,
                              void* d_out, int out_size, void* d_ws, size_t ws_size,
                              hipStream_t stream) {
  const float* enc  = (const float*)d_in[0];
  const float* dec  = (const float*)d_in[1];
  const float* Wih  = (const float*)d_in[2];
  const float* Whh  = (const float*)d_in[3];
  const float* b_ih = (const float*)d_in[4];
  const float* b_hh = (const float*)d_in[5];
  const float* fcw  = (const float*)d_in[6];
  const float* fcb  = (const float*)d_in[7];
  float* out = (float*)d_out;

  char* ws = (char*)d_ws;
  unsigned* cnt  = (unsigned*)ws; ws += 65536;
  ushort_t* xg   = (ushort_t*)ws; ws += (size_t)8 * 49 * 8192 * 2;   // 6.42 MB
  ushort_t* hA   = (ushort_t*)ws; ws += (size_t)8 * 2 * 131072 * 2;  // 4 MB
  ushort_t* innA = (ushort_t*)ws; ws += (size_t)8 * 2 * 8192 * 2;    // 256 KB
  ushort_t* nG   = (ushort_t*)ws; ws += (size_t)8 * 32 * 32768 * 2;  // 16 MB
  ushort_t* fcG  = (ushort_t*)ws; ws += (size_t)8 * 65536 * 2;       // 1 MB

  (void)hipMemsetAsync(cnt, 0, 65536, stream);
  seq2seq_xcd<<<256, 512, 0, stream>>>(
      enc, dec, Wih, Whh, b_ih, b_hh, fcw, fcb, out,
      xg, hA, innA, nG, fcG, cnt);
}

// Round 5
// 1006.284 us; speedup vs baseline: 1.3550x; 1.1279x over previous
//
#include <hip/hip_runtime.h>

// Round 11: R8 base (945us, proven) + ONE isolated delta: decoder FC is
// per-wave full-K (fcdo_w, waves 0-3; wave w owns col-tile jf=w; no scratch,
// no syncthreads) so FC blocks' waves 4-7 enter hpart immediately and FC
// overlaps hpart instead of serializing before it. inn release = per-wave
// s_waitcnt vmcnt(0) + lane0 RELAXED add (32 arrivals); fc_wait keeps R8's
// tid0-poll + syncthreads form (32 pollers, contention-safe).
// R10's per-wave barrier polling REVERTED (256 waves spinning on one L2 line
// starved the producers' atomicAdd on the same line -> 33ms outlier).

typedef unsigned short ushort_t;
typedef __bf16 bf16x8 __attribute__((ext_vector_type(8)));
typedef float f32x4 __attribute__((ext_vector_type(4)));
typedef unsigned int u32x4 __attribute__((ext_vector_type(4)));

#define MFMA(a, b, c) __builtin_amdgcn_mfma_f32_16x16x32_bf16(a, b, c, 0, 0, 0)

static __device__ __forceinline__ ushort_t f2bf(float f) {
  union { float f; unsigned u; } x; x.f = f;
  unsigned r = x.u + 0x7fffu + ((x.u >> 16) & 1u);
  return (ushort_t)(r >> 16);
}
static __device__ __forceinline__ float sigmf(float x) { return 1.f / (1.f + __expf(-x)); }
static __device__ __forceinline__ float tanhf_(float x) { return 1.f - 2.f / (__expf(2.f * x) + 1.f); }

static __device__ __forceinline__ __amdgpu_buffer_rsrc_t mkrsrc(const void* p) {
  return __builtin_amdgcn_make_buffer_rsrc(const_cast<void*>(p), (short)0, -1, 0x00020000);
}
#if __has_builtin(__builtin_amdgcn_raw_buffer_load_b128)
// aux=1 -> sc0: bypass vL1 (h/inn: written by other CUs each step).
static __device__ __forceinline__ bf16x8 ldb(__amdgpu_buffer_rsrc_t r, int voff) {
  u32x4 v = __builtin_amdgcn_raw_buffer_load_b128(r, voff, 0, 1);
  union { u32x4 u; bf16x8 b; } x; x.u = v; return x.b;
}
// aux=0: vL1-cached (weights: immutable, block/group-private).
static __device__ __forceinline__ bf16x8 ldbc(__amdgpu_buffer_rsrc_t r, int voff) {
  u32x4 v = __builtin_amdgcn_raw_buffer_load_b128(r, voff, 0, 0);
  union { u32x4 u; bf16x8 b; } x; x.u = v; return x.b;
}
#else
static __device__ __forceinline__ bf16x8 ldb(__amdgpu_buffer_rsrc_t r, int voff) {
  union { unsigned u[4]; bf16x8 b; } x;
  x.u[0] = __builtin_amdgcn_raw_buffer_load_b32(r, voff, 0, 1);
  x.u[1] = __builtin_amdgcn_raw_buffer_load_b32(r, voff + 4, 0, 1);
  x.u[2] = __builtin_amdgcn_raw_buffer_load_b32(r, voff + 8, 0, 1);
  x.u[3] = __builtin_amdgcn_raw_buffer_load_b32(r, voff + 12, 0, 1);
  return x.b;
}
static __device__ __forceinline__ bf16x8 ldbc(__amdgpu_buffer_rsrc_t r, int voff) {
  union { unsigned u[4]; bf16x8 b; } x;
  x.u[0] = __builtin_amdgcn_raw_buffer_load_b32(r, voff, 0, 0);
  x.u[1] = __builtin_amdgcn_raw_buffer_load_b32(r, voff + 4, 0, 0);
  x.u[2] = __builtin_amdgcn_raw_buffer_load_b32(r, voff + 8, 0, 0);
  x.u[3] = __builtin_amdgcn_raw_buffer_load_b32(r, voff + 12, 0, 0);
  return x.b;
}
#endif

__global__ __launch_bounds__(512, 2)
void seq2seq_xcd(const float* __restrict__ enc, const float* __restrict__ dec,
                 const float* __restrict__ Wih, const float* __restrict__ Whh,
                 const float* __restrict__ b_ih, const float* __restrict__ b_hh,
                 const float* __restrict__ fcw, const float* __restrict__ fcb,
                 float* __restrict__ outp,
                 ushort_t* __restrict__ xg, ushort_t* __restrict__ hA,
                 ushort_t* __restrict__ innA, ushort_t* __restrict__ nG,
                 ushort_t* __restrict__ fcG, unsigned* cnt) {
  __shared__ ushort_t WrzL[65536];  // [kt32][gate2][jf2][512]  128 KB
  __shared__ ushort_t WiL[6144];    // [kt2][gate3][jf2][512]    12 KB
  __shared__ float scratchF[4096];  // 4 planes x 256 slots x f32x4 (conflict-free) 16 KB
  __shared__ unsigned sgs;

  const int tid = threadIdx.x;
  const int w = tid >> 6, l = tid & 63;
  const int fr = l & 15, fq4 = l >> 4;

  // ---- claim XCD-local slot ----
  if (tid == 0) {
    unsigned x;
    asm volatile("s_getreg_b32 %0, hwreg(HW_REG_XCC_ID, 0, 8)" : "=s"(x));
    x &= 7u;
    unsigned s = atomicAdd(&cnt[x * 64], 1u);
    sgs = (x << 8) | s;
  }
  __syncthreads();
  const int g = sgs >> 8, slot = sgs & 255;
  const bool isFC = (slot >= 24);

  unsigned* arrp = cnt + (8 + g) * 64;
  auto fcpp = [&](int td) { return cnt + (48 + g * 25 + td) * 64; };

  ushort_t* hbase = hA + (size_t)g * 262144;
  auto hb = [&](int i) { return hbase + (size_t)i * 131072; };
  ushort_t* xgg = xg + (size_t)g * 49 * 8192;
  auto inng = [&](int i) { return innA + (size_t)(g * 2 + i) * 8192; };
  ushort_t* nGp = nG + (size_t)(g * 32 + slot) * 32768;
  ushort_t* fcGg = fcG + (size_t)g * 65536;

  // ---- init conversions (all group-local) ----
  for (int i = tid; i < 65536; i += 512) {  // WrzL
    int j = i & 7, ln = (i >> 3) & 63, jf = (i >> 9) & 1, gt = (i >> 10) & 1, kt = i >> 11;
    int col = gt * 1024 + slot * 32 + jf * 16 + (ln & 15);
    int k = kt * 32 + (ln >> 4) * 8 + j;
    WrzL[i] = f2bf(Whh[(size_t)col * 1024 + k]);
  }
  for (int i = tid; i < 6144; i += 512) {  // WiL (r,z,n)
    int j = i & 7, ln = (i >> 3) & 63, jf = (i >> 9) & 1, rem = i >> 10;
    int gt = rem % 3, kt = rem / 3;
    int col = gt * 1024 + slot * 32 + jf * 16 + (ln & 15);
    int k = kt * 32 + (ln >> 4) * 8 + j;
    WiL[i] = (k < 55) ? f2bf(Wih[(size_t)col * 55 + k]) : (ushort_t)0;
  }
  for (int i = tid; i < 32768; i += 512) {  // nG (block-private)
    int j = i & 7, ln = (i >> 3) & 63, jf = (i >> 9) & 1, kt = i >> 10;
    int col = 2048 + slot * 32 + jf * 16 + (ln & 15);
    int k = kt * 32 + (ln >> 4) * 8 + j;
    nGp[i] = f2bf(Whh[(size_t)col * 1024 + k]);
  }
#pragma unroll
  for (int rep = 0; rep < 2; ++rep) {  // xg: t = slot, slot+32
    int t = slot + rep * 32;
    if (t < 49) {
      ushort_t* xp = xgg + (size_t)t * 8192;
      for (int i = tid; i < 8192; i += 512) {
        int sub = i & 7, row = (i >> 3) & 127, kc = i >> 10;
        int c = kc * 8 + sub;
        xp[i] = (c < 55) ? f2bf(enc[((size_t)(g * 128 + row) * 50 + t) * 55 + c]) : (ushort_t)0;
      }
    }
  }
  if (slot < 4) {  // inn(0) = dec[:,0,:]
    ushort_t* ip = inng(0);
    for (int i = slot * 2048 + tid; i < (slot + 1) * 2048; i += 512) {
      int sub = i & 7, row = (i >> 3) & 127, kc = i >> 10;
      int c = kc * 8 + sub;
      ip[i] = (c < 55) ? f2bf(dec[(size_t)(g * 128 + row) * 1375 + c]) : (ushort_t)0;
    }
  }
  if (isFC) {  // fcG: group-shared, slot s converts kt 4(s-24)..+3
    for (int i = (slot - 24) * 8192 + tid; i < (slot - 23) * 8192; i += 512) {
      int j = i & 7, ln = (i >> 3) & 63, jf = (i >> 9) & 3, kt = i >> 11;
      int c = jf * 16 + (ln & 15);
      int k = kt * 32 + (ln >> 4) * 8 + j;
      fcGg[i] = (c < 55) ? f2bf(fcw[(size_t)c * 1024 + k]) : (ushort_t)0;
    }
  }

  // ---- per-thread constants ----
  float brz[2], bzz[2], bin[2], bhn[2];
#pragma unroll
  for (int jf = 0; jf < 2; ++jf) {
    int col = slot * 32 + jf * 16 + fr;
    brz[jf] = b_ih[col] + b_hh[col];
    bzz[jf] = b_ih[1024 + col] + b_hh[1024 + col];
    bin[jf] = b_ih[2048 + col];
    bhn[jf] = b_hh[2048 + col];
  }
  const int Rfc = (slot - 24) * 16;      // FC block rows (if isFC)
  const int jfF = w & 3;
  const int colF = jfF * 16 + fr;
  float fcbF = 0.f, inp[4] = {0.f, 0.f, 0.f, 0.f};
  if (isFC && w < 4) {
    fcbF = (colF < 55) ? fcb[colF] : 0.f;
#pragma unroll
    for (int v = 0; v < 4; ++v)
      inp[v] = (colF < 55) ? dec[(size_t)(g * 128 + Rfc + fq4 * 4 + v) * 1375 + colF] : 0.f;
  }
  f32x4 hreg[4];  // waves 0-3: [mi*2+jf]
#pragma unroll
  for (int i = 0; i < 4; ++i) hreg[i] = (f32x4){0.f, 0.f, 0.f, 0.f};

  // ---- flat group barrier (group = one XCD; no cache maintenance) ----
  auto arrive = [&](unsigned k) {
    (void)k;
    __syncthreads();  // drains vmcnt: all stores complete at (shared) L2
    if (tid == 0) atomicAdd(arrp, 1u);
  };
  auto wait_rel = [&](unsigned k) {
    __syncthreads();
    if (tid == 0) {
      while (__hip_atomic_load(arrp, __ATOMIC_RELAXED, __HIP_MEMORY_SCOPE_AGENT) < 32u * k)
        __builtin_amdgcn_s_sleep(1);
    }
    __syncthreads();
  };
  auto fc_wait = [&](int td) {  // 8 FC blocks x 4 waves = 32 wave-arrivals
    __syncthreads();
    if (tid == 0) {
      while (__hip_atomic_load(fcpp(td), __ATOMIC_RELAXED, __HIP_MEMORY_SCOPE_AGENT) < 32u)
        __builtin_amdgcn_s_sleep(1);
    }
    __syncthreads();
  };

  // ---- accumulators: r/z/nH K-split in av[12]; nX on waves 0-3 ----
  f32x4 av[12], nx[4];

  auto xpart = [&](const ushort_t* xp) {  // waves 0-3 only; full K=64
    __amdgpu_buffer_rsrc_t rx = mkrsrc(xp);
    const int R = w * 32;
#pragma unroll
    for (int kt = 0; kt < 2; ++kt) {
      bf16x8 a0 = ldb(rx, ((kt * 4 + fq4) * 128 + R + fr) * 16);
      bf16x8 a1 = ldb(rx, ((kt * 4 + fq4) * 128 + R + 16 + fr) * 16);
      const ushort_t* bl = WiL + kt * 3072 + l * 8;
#pragma unroll
      for (int jf = 0; jf < 2; ++jf) {
        bf16x8 br = *(const bf16x8*)(bl + jf * 512);
        bf16x8 bz = *(const bf16x8*)(bl + 1024 + jf * 512);
        bf16x8 bn = *(const bf16x8*)(bl + 2048 + jf * 512);
        av[jf] = MFMA(a0, br, av[jf]);
        av[2 + jf] = MFMA(a1, br, av[2 + jf]);
        av[4 + jf] = MFMA(a0, bz, av[4 + jf]);
        av[6 + jf] = MFMA(a1, bz, av[6 + jf]);
        nx[jf] = MFMA(a0, bn, nx[jf]);
        nx[2 + jf] = MFMA(a1, bn, nx[2 + jf]);
      }
    }
  };

  auto hpart = [&](const ushort_t* hbp) {  // all waves; K-split halves
    __amdgpu_buffer_rsrc_t r = mkrsrc(hbp);
    __amdgpu_buffer_rsrc_t rn = mkrsrc(nGp);
    const int kh = w >> 2, R = (w & 3) * 32;
    bf16x8 A0[4], A1[4];   // h fragments: depth-4 prefetch (sc0, L2)
    bf16x8 NG[4][2];       // n-gate weights: depth-4 prefetch (vL1)
#pragma unroll
    for (int i = 0; i < 4; ++i) {
      int kt = kh * 16 + i;
      A0[i] = ldb(r, ((kt * 4 + fq4) * 128 + R + fr) * 16);
      A1[i] = ldb(r, ((kt * 4 + fq4) * 128 + R + 16 + fr) * 16);
      NG[i][0] = ldbc(rn, kt * 2048 + l * 16);
      NG[i][1] = ldbc(rn, kt * 2048 + 1024 + l * 16);
    }
#pragma unroll
    for (int i = 0; i < 16; ++i) {
      int kt = kh * 16 + i;
      bf16x8 a0 = A0[i & 3], a1 = A1[i & 3];
      bf16x8 n0 = NG[i & 3][0], n1 = NG[i & 3][1];
      if (i < 12) {
        int kp = kt + 4;
        A0[i & 3] = ldb(r, ((kp * 4 + fq4) * 128 + R + fr) * 16);
        A1[i & 3] = ldb(r, ((kp * 4 + fq4) * 128 + R + 16 + fr) * 16);
        NG[i & 3][0] = ldbc(rn, kp * 2048 + l * 16);
        NG[i & 3][1] = ldbc(rn, kp * 2048 + 1024 + l * 16);
      }
      const ushort_t* bl = WrzL + kt * 2048 + l * 8;
#pragma unroll
      for (int jf = 0; jf < 2; ++jf) {
        bf16x8 br = *(const bf16x8*)(bl + jf * 512);
        bf16x8 bz = *(const bf16x8*)(bl + 1024 + jf * 512);
        bf16x8 bn = (jf == 0) ? n0 : n1;
        av[jf] = MFMA(a0, br, av[jf]);
        av[2 + jf] = MFMA(a1, br, av[2 + jf]);
        av[4 + jf] = MFMA(a0, bz, av[4 + jf]);
        av[6 + jf] = MFMA(a1, bz, av[6 + jf]);
        av[8 + jf] = MFMA(a0, bn, av[8 + jf]);
        av[10 + jf] = MFMA(a1, bn, av[10 + jf]);
      }
    }
  };

  // waves 4-7 partials -> waves 0-3. Plane layout: scratchF[r*1024 + slot*4],
  // slot = wave4*64 + lane -> 16B/lane contiguous per wave => conflict-free.
  auto kreduce = [&]() {
#pragma unroll
    for (int rd = 0; rd < 3; ++rd) {
      if (w >= 4) {
        float* sp = scratchF + ((w - 4) * 64 + l) * 4;
#pragma unroll
        for (int r = 0; r < 4; ++r)
          *(f32x4*)(sp + r * 1024) = av[rd * 4 + r];
      }
      __syncthreads();
      if (w < 4) {
        const float* sp = scratchF + (w * 64 + l) * 4;
#pragma unroll
        for (int r = 0; r < 4; ++r)
          av[rd * 4 + r] += *(const f32x4*)(sp + r * 1024);
      }
      __syncthreads();
    }
  };

  // FC: full-K per-wave (waves 0-3 only; wave w owns col-tile jf=w).
  // No scratch, no syncthreads -> waves 4-7 of FC blocks enter hpart at once.
  auto fcdo_w = [&](const ushort_t* hbp, int td, bool wr, ushort_t* innW) {
    __amdgpu_buffer_rsrc_t r = mkrsrc(hbp);
    __amdgpu_buffer_rsrc_t rf = mkrsrc(fcGg);
    f32x4 fa4[4];
#pragma unroll
    for (int i = 0; i < 4; ++i) fa4[i] = (f32x4){0.f, 0.f, 0.f, 0.f};
    bf16x8 Af[4], Bf[4];
#pragma unroll
    for (int i = 0; i < 4; ++i) {
      Af[i] = ldb(r, ((i * 4 + fq4) * 128 + Rfc + fr) * 16);
      Bf[i] = ldbc(rf, (i * 4 + jfF) * 1024 + l * 16);
    }
#pragma unroll
    for (int i = 0; i < 32; ++i) {
      bf16x8 a = Af[i & 3], bb = Bf[i & 3];
      if (i < 28) {
        Af[i & 3] = ldb(r, (((i + 4) * 4 + fq4) * 128 + Rfc + fr) * 16);
        Bf[i & 3] = ldbc(rf, ((i + 4) * 4 + jfF) * 1024 + l * 16);
      }
      fa4[i & 3] = MFMA(a, bb, fa4[i & 3]);
    }
    f32x4 fa = (fa4[0] + fa4[1]) + (fa4[2] + fa4[3]);
    const int kq = colF >> 3, sub = colF & 7;
#pragma unroll
    for (int v = 0; v < 4; ++v) {
      int row = Rfc + fq4 * 4 + v;
      float o = fa[v] + inp[v] + fcbF;
      inp[v] = o;
      if (wr) innW[(kq * 128 + row) * 8 + sub] = f2bf(o);
      if (colF < 55) outp[(size_t)(g * 128 + row) * 1375 + td * 55 + colF] = o;
    }
    if (wr) {
      asm volatile("s_waitcnt vmcnt(0)" ::: "memory");  // inn stores at L2
      if (l == 0)
        __hip_atomic_fetch_add(fcpp(td), 1u, __ATOMIC_RELAXED, __HIP_MEMORY_SCOPE_AGENT);
    }
  };

  arrive(1);
  wait_rel(1);

  for (int t = 0; t < 74; ++t) {
#pragma unroll
    for (int i = 0; i < 12; ++i) av[i] = (f32x4){0.f, 0.f, 0.f, 0.f};
#pragma unroll
    for (int i = 0; i < 4; ++i) nx[i] = (f32x4){0.f, 0.f, 0.f, 0.f};

    if (t <= 49) {
      if (w < 4) xpart(t <= 48 ? xgg + (size_t)t * 8192 : inng(0));
    }
    if (t > 0) wait_rel(t + 1);
    if (t >= 50 && isFC && w < 4)
      fcdo_w(hb(t & 1), t - 50, true, inng((t - 49) & 1));
    if (t > 0) hpart(hb(t & 1));
    if (t >= 50) {
      fc_wait(t - 50);
      if (w < 4) xpart(inng((t - 49) & 1));
    }
    kreduce();
    if (w < 4) {  // epilogue: gates + fp32 carry + publish bf16 h(t+1)
      ushort_t* hn = hb((t + 1) & 1);
#pragma unroll
      for (int mi = 0; mi < 2; ++mi)
#pragma unroll
        for (int jf = 0; jf < 2; ++jf) {
          f32x4 R_ = av[mi * 2 + jf], Z_ = av[4 + mi * 2 + jf];
          f32x4 NH = av[8 + mi * 2 + jf], NX = nx[mi * 2 + jf];
          const int kq = slot * 4 + jf * 2 + (fr >> 3), sub = fr & 7;
#pragma unroll
          for (int v = 0; v < 4; ++v) {
            float rr = sigmf(R_[v] + brz[jf]);
            float zz = sigmf(Z_[v] + bzz[jf]);
            float nn = tanhf_(NX[v] + bin[jf] + rr * (NH[v] + bhn[jf]));
            float h = (1.f - zz) * nn + zz * hreg[mi * 2 + jf][v];
            hreg[mi * 2 + jf][v] = h;
            int row = w * 32 + mi * 16 + fq4 * 4 + v;
            hn[(kq * 128 + row) * 8 + sub] = f2bf(h);
          }
        }
    }
    arrive(t + 2);
  }

  if (isFC) {
    wait_rel(75);
    if (w < 4) fcdo_w(hb(0), 24, false, (ushort_t*)0);
  }
}

extern "C" void kernel_launch(void* const* d_in, const int* in_sizes, int n_in,
                              void* d_out, int out_size, void* d_ws, size_t ws_size,
                              hipStream_t stream) {
  const float* enc  = (const float*)d_in[0];
  const float* dec  = (const float*)d_in[1];
  const float* Wih  = (const float*)d_in[2];
  const float* Whh  = (const float*)d_in[3];
  const float* b_ih = (const float*)d_in[4];
  const float* b_hh = (const float*)d_in[5];
  const float* fcw  = (const float*)d_in[6];
  const float* fcb  = (const float*)d_in[7];
  float* out = (float*)d_out;

  char* ws = (char*)d_ws;
  unsigned* cnt  = (unsigned*)ws; ws += 65536;
  ushort_t* xg   = (ushort_t*)ws; ws += (size_t)8 * 49 * 8192 * 2;   // 6.42 MB
  ushort_t* hA   = (ushort_t*)ws; ws += (size_t)8 * 2 * 131072 * 2;  // 4 MB
  ushort_t* innA = (ushort_t*)ws; ws += (size_t)8 * 2 * 8192 * 2;    // 256 KB
  ushort_t* nG   = (ushort_t*)ws; ws += (size_t)8 * 32 * 32768 * 2;  // 16 MB
  ushort_t* fcG  = (ushort_t*)ws; ws += (size_t)8 * 65536 * 2;       // 1 MB

  (void)hipMemsetAsync(cnt, 0, 65536, stream);
  seq2seq_xcd<<<256, 512, 0, stream>>>(
      enc, dec, Wih, Whh, b_ih, b_hh, fcw, fcb, out,
      xg, hA, innA, nG, fcG, cnt);
}

// Round 6
// 801.364 us; speedup vs baseline: 1.7015x; 1.2557x over previous
//
#include <hip/hip_runtime.h>

// Round 12: R8 base restored (945us champion; R9/R10/R11 deltas all reverted)
// + two low-risk latency cuts:
//  (a) hpart: cross-iteration prefetch of the 4 WrzL ds_read_b128 fragments
//      (+16 VGPR). B-frags were read and consumed in the same iter (~120cy
//      lgkm stall x16, both SIMD waves phase-locked so they stall together);
//      now read one iter ahead (~233cy of MFMA issue covers the latency).
//  (b) redundant __syncthreads removed: wait_rel/fc_wait leading sync
//      (arrive's barrier directly precedes, only register work between) and
//      fc_arrive's extra barrier (fcdo's trailing barrier already drains
//      vmcnt -> inn stores at L2 before tid0 signals).
// fcdo stays BLOCK-WIDE (R11's per-wave full-K doubled waves0-3 FC work and
// FC h-reads -> +50us; reverted).

typedef unsigned short ushort_t;
typedef __bf16 bf16x8 __attribute__((ext_vector_type(8)));
typedef float f32x4 __attribute__((ext_vector_type(4)));
typedef unsigned int u32x4 __attribute__((ext_vector_type(4)));

#define MFMA(a, b, c) __builtin_amdgcn_mfma_f32_16x16x32_bf16(a, b, c, 0, 0, 0)

static __device__ __forceinline__ ushort_t f2bf(float f) {
  union { float f; unsigned u; } x; x.f = f;
  unsigned r = x.u + 0x7fffu + ((x.u >> 16) & 1u);
  return (ushort_t)(r >> 16);
}
static __device__ __forceinline__ float sigmf(float x) { return 1.f / (1.f + __expf(-x)); }
static __device__ __forceinline__ float tanhf_(float x) { return 1.f - 2.f / (__expf(2.f * x) + 1.f); }

static __device__ __forceinline__ __amdgpu_buffer_rsrc_t mkrsrc(const void* p) {
  return __builtin_amdgcn_make_buffer_rsrc(const_cast<void*>(p), (short)0, -1, 0x00020000);
}
#if __has_builtin(__builtin_amdgcn_raw_buffer_load_b128)
// aux=1 -> sc0: bypass vL1 (h/inn: written by other CUs each step).
static __device__ __forceinline__ bf16x8 ldb(__amdgpu_buffer_rsrc_t r, int voff) {
  u32x4 v = __builtin_amdgcn_raw_buffer_load_b128(r, voff, 0, 1);
  union { u32x4 u; bf16x8 b; } x; x.u = v; return x.b;
}
// aux=0: vL1-cached (weights: immutable, block/group-private).
static __device__ __forceinline__ bf16x8 ldbc(__amdgpu_buffer_rsrc_t r, int voff) {
  u32x4 v = __builtin_amdgcn_raw_buffer_load_b128(r, voff, 0, 0);
  union { u32x4 u; bf16x8 b; } x; x.u = v; return x.b;
}
#else
static __device__ __forceinline__ bf16x8 ldb(__amdgpu_buffer_rsrc_t r, int voff) {
  union { unsigned u[4]; bf16x8 b; } x;
  x.u[0] = __builtin_amdgcn_raw_buffer_load_b32(r, voff, 0, 1);
  x.u[1] = __builtin_amdgcn_raw_buffer_load_b32(r, voff + 4, 0, 1);
  x.u[2] = __builtin_amdgcn_raw_buffer_load_b32(r, voff + 8, 0, 1);
  x.u[3] = __builtin_amdgcn_raw_buffer_load_b32(r, voff + 12, 0, 1);
  return x.b;
}
static __device__ __forceinline__ bf16x8 ldbc(__amdgpu_buffer_rsrc_t r, int voff) {
  union { unsigned u[4]; bf16x8 b; } x;
  x.u[0] = __builtin_amdgcn_raw_buffer_load_b32(r, voff, 0, 0);
  x.u[1] = __builtin_amdgcn_raw_buffer_load_b32(r, voff + 4, 0, 0);
  x.u[2] = __builtin_amdgcn_raw_buffer_load_b32(r, voff + 8, 0, 0);
  x.u[3] = __builtin_amdgcn_raw_buffer_load_b32(r, voff + 12, 0, 0);
  return x.b;
}
#endif

__global__ __launch_bounds__(512, 2)
void seq2seq_xcd(const float* __restrict__ enc, const float* __restrict__ dec,
                 const float* __restrict__ Wih, const float* __restrict__ Whh,
                 const float* __restrict__ b_ih, const float* __restrict__ b_hh,
                 const float* __restrict__ fcw, const float* __restrict__ fcb,
                 float* __restrict__ outp,
                 ushort_t* __restrict__ xg, ushort_t* __restrict__ hA,
                 ushort_t* __restrict__ innA, ushort_t* __restrict__ nG,
                 ushort_t* __restrict__ fcG, unsigned* cnt) {
  __shared__ ushort_t WrzL[65536];  // [kt32][gate2][jf2][512]  128 KB
  __shared__ ushort_t WiL[6144];    // [kt2][gate3][jf2][512]    12 KB
  __shared__ float scratchF[4096];  // 4 planes x 256 slots x f32x4 (conflict-free) 16 KB
  __shared__ unsigned sgs;

  const int tid = threadIdx.x;
  const int w = tid >> 6, l = tid & 63;
  const int fr = l & 15, fq4 = l >> 4;

  // ---- claim XCD-local slot ----
  if (tid == 0) {
    unsigned x;
    asm volatile("s_getreg_b32 %0, hwreg(HW_REG_XCC_ID, 0, 8)" : "=s"(x));
    x &= 7u;
    unsigned s = atomicAdd(&cnt[x * 64], 1u);
    sgs = (x << 8) | s;
  }
  __syncthreads();
  const int g = sgs >> 8, slot = sgs & 255;
  const bool isFC = (slot >= 24);

  unsigned* arrp = cnt + (8 + g) * 64;
  auto fcpp = [&](int td) { return cnt + (48 + g * 25 + td) * 64; };

  ushort_t* hbase = hA + (size_t)g * 262144;
  auto hb = [&](int i) { return hbase + (size_t)i * 131072; };
  ushort_t* xgg = xg + (size_t)g * 49 * 8192;
  auto inng = [&](int i) { return innA + (size_t)(g * 2 + i) * 8192; };
  ushort_t* nGp = nG + (size_t)(g * 32 + slot) * 32768;
  ushort_t* fcGg = fcG + (size_t)g * 65536;

  // ---- init conversions (all group-local) ----
  for (int i = tid; i < 65536; i += 512) {  // WrzL
    int j = i & 7, ln = (i >> 3) & 63, jf = (i >> 9) & 1, gt = (i >> 10) & 1, kt = i >> 11;
    int col = gt * 1024 + slot * 32 + jf * 16 + (ln & 15);
    int k = kt * 32 + (ln >> 4) * 8 + j;
    WrzL[i] = f2bf(Whh[(size_t)col * 1024 + k]);
  }
  for (int i = tid; i < 6144; i += 512) {  // WiL (r,z,n)
    int j = i & 7, ln = (i >> 3) & 63, jf = (i >> 9) & 1, rem = i >> 10;
    int gt = rem % 3, kt = rem / 3;
    int col = gt * 1024 + slot * 32 + jf * 16 + (ln & 15);
    int k = kt * 32 + (ln >> 4) * 8 + j;
    WiL[i] = (k < 55) ? f2bf(Wih[(size_t)col * 55 + k]) : (ushort_t)0;
  }
  for (int i = tid; i < 32768; i += 512) {  // nG (block-private)
    int j = i & 7, ln = (i >> 3) & 63, jf = (i >> 9) & 1, kt = i >> 10;
    int col = 2048 + slot * 32 + jf * 16 + (ln & 15);
    int k = kt * 32 + (ln >> 4) * 8 + j;
    nGp[i] = f2bf(Whh[(size_t)col * 1024 + k]);
  }
#pragma unroll
  for (int rep = 0; rep < 2; ++rep) {  // xg: t = slot, slot+32
    int t = slot + rep * 32;
    if (t < 49) {
      ushort_t* xp = xgg + (size_t)t * 8192;
      for (int i = tid; i < 8192; i += 512) {
        int sub = i & 7, row = (i >> 3) & 127, kc = i >> 10;
        int c = kc * 8 + sub;
        xp[i] = (c < 55) ? f2bf(enc[((size_t)(g * 128 + row) * 50 + t) * 55 + c]) : (ushort_t)0;
      }
    }
  }
  if (slot < 4) {  // inn(0) = dec[:,0,:]
    ushort_t* ip = inng(0);
    for (int i = slot * 2048 + tid; i < (slot + 1) * 2048; i += 512) {
      int sub = i & 7, row = (i >> 3) & 127, kc = i >> 10;
      int c = kc * 8 + sub;
      ip[i] = (c < 55) ? f2bf(dec[(size_t)(g * 128 + row) * 1375 + c]) : (ushort_t)0;
    }
  }
  if (isFC) {  // fcG: group-shared, slot s converts kt 4(s-24)..+3
    for (int i = (slot - 24) * 8192 + tid; i < (slot - 23) * 8192; i += 512) {
      int j = i & 7, ln = (i >> 3) & 63, jf = (i >> 9) & 3, kt = i >> 11;
      int c = jf * 16 + (ln & 15);
      int k = kt * 32 + (ln >> 4) * 8 + j;
      fcGg[i] = (c < 55) ? f2bf(fcw[(size_t)c * 1024 + k]) : (ushort_t)0;
    }
  }

  // ---- per-thread constants ----
  float brz[2], bzz[2], bin[2], bhn[2];
#pragma unroll
  for (int jf = 0; jf < 2; ++jf) {
    int col = slot * 32 + jf * 16 + fr;
    brz[jf] = b_ih[col] + b_hh[col];
    bzz[jf] = b_ih[1024 + col] + b_hh[1024 + col];
    bin[jf] = b_ih[2048 + col];
    bhn[jf] = b_hh[2048 + col];
  }
  const int Rfc = (slot - 24) * 16;      // FC block rows (if isFC)
  const int jfF = w & 3;
  const int colF = jfF * 16 + fr;
  float fcbF = 0.f, inp[4] = {0.f, 0.f, 0.f, 0.f};
  if (isFC && w < 4) {
    fcbF = (colF < 55) ? fcb[colF] : 0.f;
#pragma unroll
    for (int v = 0; v < 4; ++v)
      inp[v] = (colF < 55) ? dec[(size_t)(g * 128 + Rfc + fq4 * 4 + v) * 1375 + colF] : 0.f;
  }
  f32x4 hreg[4];  // waves 0-3: [mi*2+jf]
#pragma unroll
  for (int i = 0; i < 4; ++i) hreg[i] = (f32x4){0.f, 0.f, 0.f, 0.f};

  // ---- flat group barrier (group = one XCD; no cache maintenance) ----
  auto arrive = [&](unsigned k) {
    (void)k;
    __syncthreads();  // drains vmcnt: all stores complete at (shared) L2
    if (tid == 0) atomicAdd(arrp, 1u);
  };
  auto wait_rel = [&](unsigned k) {  // leading sync dropped: arrive's barrier
    if (tid == 0) {                  // directly precedes with register-only work between
      while (__hip_atomic_load(arrp, __ATOMIC_RELAXED, __HIP_MEMORY_SCOPE_AGENT) < 32u * k)
        __builtin_amdgcn_s_sleep(1);
    }
    __syncthreads();
  };
  auto fc_wait = [&](int td) {
    if (tid == 0) {
      while (__hip_atomic_load(fcpp(td), __ATOMIC_RELAXED, __HIP_MEMORY_SCOPE_AGENT) < 8u)
        __builtin_amdgcn_s_sleep(1);
    }
    __syncthreads();
  };

  // ---- accumulators: r/z/nH K-split in av[12]; nX on waves 0-3 ----
  f32x4 av[12], nx[4];

  auto xpart = [&](const ushort_t* xp) {  // waves 0-3 only; full K=64
    __amdgpu_buffer_rsrc_t rx = mkrsrc(xp);
    const int R = w * 32;
#pragma unroll
    for (int kt = 0; kt < 2; ++kt) {
      bf16x8 a0 = ldb(rx, ((kt * 4 + fq4) * 128 + R + fr) * 16);
      bf16x8 a1 = ldb(rx, ((kt * 4 + fq4) * 128 + R + 16 + fr) * 16);
      const ushort_t* bl = WiL + kt * 3072 + l * 8;
#pragma unroll
      for (int jf = 0; jf < 2; ++jf) {
        bf16x8 br = *(const bf16x8*)(bl + jf * 512);
        bf16x8 bz = *(const bf16x8*)(bl + 1024 + jf * 512);
        bf16x8 bn = *(const bf16x8*)(bl + 2048 + jf * 512);
        av[jf] = MFMA(a0, br, av[jf]);
        av[2 + jf] = MFMA(a1, br, av[2 + jf]);
        av[4 + jf] = MFMA(a0, bz, av[4 + jf]);
        av[6 + jf] = MFMA(a1, bz, av[6 + jf]);
        nx[jf] = MFMA(a0, bn, nx[jf]);
        nx[2 + jf] = MFMA(a1, bn, nx[2 + jf]);
      }
    }
  };

  auto hpart = [&](const ushort_t* hbp) {  // all waves; K-split halves
    __amdgpu_buffer_rsrc_t r = mkrsrc(hbp);
    __amdgpu_buffer_rsrc_t rn = mkrsrc(nGp);
    const int kh = w >> 2, R = (w & 3) * 32;
    bf16x8 A0[4], A1[4];   // h fragments: depth-4 prefetch (sc0, L2)
    bf16x8 NG[4][2];       // n-gate weights: depth-4 prefetch (vL1)
#pragma unroll
    for (int i = 0; i < 4; ++i) {
      int kt = kh * 16 + i;
      A0[i] = ldb(r, ((kt * 4 + fq4) * 128 + R + fr) * 16);
      A1[i] = ldb(r, ((kt * 4 + fq4) * 128 + R + 16 + fr) * 16);
      NG[i][0] = ldbc(rn, kt * 2048 + l * 16);
      NG[i][1] = ldbc(rn, kt * 2048 + 1024 + l * 16);
    }
    // LDS B-frags: cross-iteration prefetch (depth-1, +16 VGPR)
    const ushort_t* bl0 = WrzL + (kh * 16) * 2048 + l * 8;
    bf16x8 br0 = *(const bf16x8*)(bl0);
    bf16x8 br1 = *(const bf16x8*)(bl0 + 512);
    bf16x8 bz0 = *(const bf16x8*)(bl0 + 1024);
    bf16x8 bz1 = *(const bf16x8*)(bl0 + 1536);
#pragma unroll
    for (int i = 0; i < 16; ++i) {
      int kt = kh * 16 + i;
      bf16x8 a0 = A0[i & 3], a1 = A1[i & 3];
      bf16x8 n0 = NG[i & 3][0], n1 = NG[i & 3][1];
      bf16x8 cr0 = br0, cr1 = br1, cz0 = bz0, cz1 = bz1;
      if (i < 15) {  // prefetch next iter's WrzL fragments
        const ushort_t* bln = WrzL + (kt + 1) * 2048 + l * 8;
        br0 = *(const bf16x8*)(bln);
        br1 = *(const bf16x8*)(bln + 512);
        bz0 = *(const bf16x8*)(bln + 1024);
        bz1 = *(const bf16x8*)(bln + 1536);
      }
      if (i < 12) {
        int kp = kt + 4;
        A0[i & 3] = ldb(r, ((kp * 4 + fq4) * 128 + R + fr) * 16);
        A1[i & 3] = ldb(r, ((kp * 4 + fq4) * 128 + R + 16 + fr) * 16);
        NG[i & 3][0] = ldbc(rn, kp * 2048 + l * 16);
        NG[i & 3][1] = ldbc(rn, kp * 2048 + 1024 + l * 16);
      }
      av[0] = MFMA(a0, cr0, av[0]);
      av[2] = MFMA(a1, cr0, av[2]);
      av[1] = MFMA(a0, cr1, av[1]);
      av[3] = MFMA(a1, cr1, av[3]);
      av[4] = MFMA(a0, cz0, av[4]);
      av[6] = MFMA(a1, cz0, av[6]);
      av[5] = MFMA(a0, cz1, av[5]);
      av[7] = MFMA(a1, cz1, av[7]);
      av[8] = MFMA(a0, n0, av[8]);
      av[10] = MFMA(a1, n0, av[10]);
      av[9] = MFMA(a0, n1, av[9]);
      av[11] = MFMA(a1, n1, av[11]);
    }
  };

  // waves 4-7 partials -> waves 0-3. Plane layout: scratchF[r*1024 + slot*4],
  // slot = wave4*64 + lane -> 16B/lane contiguous per wave => conflict-free.
  auto kreduce = [&]() {
#pragma unroll
    for (int rd = 0; rd < 3; ++rd) {
      if (w >= 4) {
        float* sp = scratchF + ((w - 4) * 64 + l) * 4;
#pragma unroll
        for (int r = 0; r < 4; ++r)
          *(f32x4*)(sp + r * 1024) = av[rd * 4 + r];
      }
      __syncthreads();
      if (w < 4) {
        const float* sp = scratchF + (w * 64 + l) * 4;
#pragma unroll
        for (int r = 0; r < 4; ++r)
          av[rd * 4 + r] += *(const f32x4*)(sp + r * 1024);
      }
      __syncthreads();
    }
  };

  auto fcdo = [&](const ushort_t* hbp, int td, bool wr, ushort_t* innW) {
    __amdgpu_buffer_rsrc_t r = mkrsrc(hbp);
    __amdgpu_buffer_rsrc_t rf = mkrsrc(fcGg);
    const int kh = w >> 2;
    f32x4 fa = (f32x4){0.f, 0.f, 0.f, 0.f};
    bf16x8 Af[4], Bf[4];
#pragma unroll
    for (int i = 0; i < 4; ++i) {
      int kt = kh * 16 + i;
      Af[i] = ldb(r, ((kt * 4 + fq4) * 128 + Rfc + fr) * 16);
      Bf[i] = ldbc(rf, (kt * 4 + jfF) * 1024 + l * 16);
    }
#pragma unroll
    for (int i = 0; i < 16; ++i) {
      int kt = kh * 16 + i;
      bf16x8 a = Af[i & 3], bb = Bf[i & 3];
      if (i < 12) {
        Af[i & 3] = ldb(r, (((kt + 4) * 4 + fq4) * 128 + Rfc + fr) * 16);
        Bf[i & 3] = ldbc(rf, ((kt + 4) * 4 + jfF) * 1024 + l * 16);
      }
      fa = MFMA(a, bb, fa);
    }
    if (w >= 4) *(f32x4*)(scratchF + ((w - 4) * 64 + l) * 4) = fa;
    __syncthreads();
    if (w < 4) {
      fa += *(const f32x4*)(scratchF + (w * 64 + l) * 4);
      const int kq = colF >> 3, sub = colF & 7;
#pragma unroll
      for (int v = 0; v < 4; ++v) {
        int row = Rfc + fq4 * 4 + v;
        float o = fa[v] + inp[v] + fcbF;
        inp[v] = o;
        if (wr) innW[(kq * 128 + row) * 8 + sub] = f2bf(o);
        if (colF < 55) outp[(size_t)(g * 128 + row) * 1375 + td * 55 + colF] = o;
      }
    }
    __syncthreads();  // drains all waves' inn/out stores to L2
  };

  arrive(1);
  wait_rel(1);

  for (int t = 0; t < 74; ++t) {
#pragma unroll
    for (int i = 0; i < 12; ++i) av[i] = (f32x4){0.f, 0.f, 0.f, 0.f};
#pragma unroll
    for (int i = 0; i < 4; ++i) nx[i] = (f32x4){0.f, 0.f, 0.f, 0.f};

    if (t <= 49) {
      if (w < 4) xpart(t <= 48 ? xgg + (size_t)t * 8192 : inng(0));
    }
    if (t > 0) wait_rel(t + 1);
    if (t >= 50 && isFC) {
      fcdo(hb(t & 1), t - 50, true, inng((t - 49) & 1));
      if (tid == 0) atomicAdd(fcpp(t - 50), 1u);  // fcdo's barrier drained stores
    }
    if (t > 0) hpart(hb(t & 1));
    if (t >= 50) {
      fc_wait(t - 50);
      if (w < 4) xpart(inng((t - 49) & 1));
    }
    kreduce();
    if (w < 4) {  // epilogue: gates + fp32 carry + publish bf16 h(t+1)
      ushort_t* hn = hb((t + 1) & 1);
#pragma unroll
      for (int mi = 0; mi < 2; ++mi)
#pragma unroll
        for (int jf = 0; jf < 2; ++jf) {
          f32x4 R_ = av[mi * 2 + jf], Z_ = av[4 + mi * 2 + jf];
          f32x4 NH = av[8 + mi * 2 + jf], NX = nx[mi * 2 + jf];
          const int kq = slot * 4 + jf * 2 + (fr >> 3), sub = fr & 7;
#pragma unroll
          for (int v = 0; v < 4; ++v) {
            float rr = sigmf(R_[v] + brz[jf]);
            float zz = sigmf(Z_[v] + bzz[jf]);
            float nn = tanhf_(NX[v] + bin[jf] + rr * (NH[v] + bhn[jf]));
            float h = (1.f - zz) * nn + zz * hreg[mi * 2 + jf][v];
            hreg[mi * 2 + jf][v] = h;
            int row = w * 32 + mi * 16 + fq4 * 4 + v;
            hn[(kq * 128 + row) * 8 + sub] = f2bf(h);
          }
        }
    }
    arrive(t + 2);
  }

  if (isFC) {
    wait_rel(75);
    fcdo(hb(0), 24, false, (ushort_t*)0);
  }
}

extern "C" void kernel_launch(void* const* d_in, const int* in_sizes, int n_in,
                              void* d_out, int out_size, void* d_ws, size_t ws_size,
                              hipStream_t stream) {
  const float* enc  = (const float*)d_in[0];
  const float* dec  = (const float*)d_in[1];
  const float* Wih  = (const float*)d_in[2];
  const float* Whh  = (const float*)d_in[3];
  const float* b_ih = (const float*)d_in[4];
  const float* b_hh = (const float*)d_in[5];
  const float* fcw  = (const float*)d_in[6];
  const float* fcb  = (const float*)d_in[7];
  float* out = (float*)d_out;

  char* ws = (char*)d_ws;
  unsigned* cnt  = (unsigned*)ws; ws += 65536;
  ushort_t* xg   = (ushort_t*)ws; ws += (size_t)8 * 49 * 8192 * 2;   // 6.42 MB
  ushort_t* hA   = (ushort_t*)ws; ws += (size_t)8 * 2 * 131072 * 2;  // 4 MB
  ushort_t* innA = (ushort_t*)ws; ws += (size_t)8 * 2 * 8192 * 2;    // 256 KB
  ushort_t* nG   = (ushort_t*)ws; ws += (size_t)8 * 32 * 32768 * 2;  // 16 MB
  ushort_t* fcG  = (ushort_t*)ws; ws += (size_t)8 * 65536 * 2;       // 1 MB

  (void)hipMemsetAsync(cnt, 0, 65536, stream);
  seq2seq_xcd<<<256, 512, 0, stream>>>(
      enc, dec, Wih, Whh, b_ih, b_hh, fcw, fcb, out,
      xg, hA, innA, nG, fcG, cnt);
}